// Round 18
// baseline (50.153 us; speedup 1.0000x reference)
//
#include <hip/hip_runtime.h>

#define GDIM 38
#define GG   (GDIM * GDIM)          // 1444
#define TOTAL (GDIM * GDIM * GDIM)  // 54872
#define QTR   (TOTAL / 4)           // 13718 buckets per quarter
#define QWORDS (QTR / 2)            // 6859 packed u32 words per quarter
#define NSLICE 64                   // atom slices for histogram
#define BS 256
#define NCHUNK ((TOTAL + 255) / 256)   // 215

typedef float f32x4 __attribute__((ext_vector_type(4)));

// packed (disp+1) per k: dx | dy<<8 | dz<<16
__device__ __constant__ unsigned int c_dp[13] = {
    0x010100u, 0x010000u, 0x010001u, 0x010002u,
    0x000200u, 0x000201u, 0x000202u,
    0x000100u, 0x000101u, 0x000102u,
    0x000000u, 0x000001u, 0x000002u};

// translation-case table bit-packed: 5 bits/entry (verified R13/R15/R16/R17)
__device__ __forceinline__ int case_of(int cidx) {
    constexpr unsigned long long W0 = 11ULL | (2ULL << 5) | (8ULL << 15) | (1ULL << 20)
        | (5ULL << 30) | (14ULL << 35) | (12ULL << 45) | (3ULL << 50);
    constexpr unsigned long long W1 = 9ULL | (6ULL << 15) | (15ULL << 20)
        | (13ULL << 30) | (4ULL << 35) | (10ULL << 45) | (17ULL << 50);
    constexpr unsigned long long W2 = 7ULL | (16ULL << 5);
    unsigned long long wv = cidx < 12 ? W0 : (cidx < 24 ? W1 : W2);
    int base = cidx < 12 ? 0 : (cidx < 24 ? 12 : 24);
    return (int)((wv >> (5 * (cidx - base))) & 31ULL);
}

// Atoms: wave-private LDS staging, 16 KB/block -> 8 blocks/CU (32 waves/CU).
__global__ __launch_bounds__(BS, 8) void cell_atoms_kernel(
    const float* __restrict__ coords, const float* __restrict__ cell,
    float* __restrict__ out, int N)
{
    __shared__ float s[4096];               // 16 KB: 4 waves x (192 + 832)
    const int tid = threadIdx.x;
    const int w = tid >> 6, lane = tid & 63;
    const long long wbase = (long long)blockIdx.x * BS + 64 * w;
    if (wbase >= N) return;

    float* sc = s + 1024 * w;               // 192 floats: coords -> frac in place
    float* sb = sc + 192;                   // 832 floats: nf then nc

    const long long OFF1 = 3LL * N, OFF2 = 4LL * N, OFF3 = 17LL * N;
    const bool fullwave = (wbase + 64 <= N);
    const int nval = fullwave ? 64 : (int)(N - wbase);

    if (fullwave) {
        const f32x4* src = (const f32x4*)(coords + wbase * 3);
        if (lane < 48) ((f32x4*)sc)[lane] = src[lane];
    } else {
        const float* src = coords + wbase * 3;
        for (int j = lane; j < nval * 3; j += 64) sc[j] = src[j];
    }

    float ncv[13];
    if (lane < nval) {
        const float d0 = cell[0], d4 = cell[4], d8 = cell[8];
        int v[3];
#pragma unroll
        for (int a = 0; a < 3; ++a) {
            float d = (a == 0) ? d0 : (a == 1 ? d4 : d8);
            float f = sc[3 * lane + a] / d;   // IEEE divide, matches jnp
            f = f - floorf(f);
            if (f >= 1.0f) f -= 1.0f;
            if (f < 0.0f)  f += 1.0f;
            sc[3 * lane + a] = f;             // frac in place
            v[a] = (int)floorf(f * (float)GDIM);
        }
        int flat = v[0] * GG + v[1] * GDIM + v[2];
        out[OFF1 + wbase + lane] = (float)flat;   // PLAIN: re-read by hist (L2)

#pragma unroll
        for (int k = 0; k < 13; ++k) {
            const unsigned int dp = c_dp[k];
            const int n0 = v[0] + (int)(dp & 0xFFu);
            const int n1 = v[1] + (int)((dp >> 8) & 0xFFu);
            const int n2 = v[2] + (int)((dp >> 16) & 0xFFu);
            const int m0 = (n0 == 0) ? (GDIM - 1) : ((n0 == GDIM + 1) ? 0 : n0 - 1);
            const int m1 = (n1 == 0) ? (GDIM - 1) : ((n1 == GDIM + 1) ? 0 : n1 - 1);
            const int m2 = (n2 == 0) ? (GDIM - 1) : ((n2 == GDIM + 1) ? 0 : n2 - 1);
            const int c0 = (n0 == 0) ? 0 : ((n0 == GDIM + 1) ? 2 : 1);
            const int c1 = (n1 == 0) ? 0 : ((n1 == GDIM + 1) ? 2 : 1);
            const int c2 = (n2 == 0) ? 0 : ((n2 == GDIM + 1) ? 2 : 1);
            sb[13 * lane + k] = (float)(m0 * GG + m1 * GDIM + m2);
            ncv[k] = (float)case_of(c0 * 9 + c1 * 3 + c2);
        }
    }

    if (fullwave) {
        f32x4* dfr = (f32x4*)(out + wbase * 3);
        if (lane < 48) __builtin_nontemporal_store(((f32x4*)sc)[lane], &dfr[lane]);

        f32x4* dnf = (f32x4*)(out + OFF2 + wbase * 13);
#pragma unroll
        for (int j = lane; j < 208; j += 64)
            __builtin_nontemporal_store(((f32x4*)sb)[j], &dnf[j]);

        // reuse sb for nc (same-wave LDS ordering guarantees nf reads done)
#pragma unroll
        for (int k = 0; k < 13; ++k) sb[13 * lane + k] = ncv[k];

        f32x4* dnc = (f32x4*)(out + OFF3 + wbase * 13);
#pragma unroll
        for (int j = lane; j < 208; j += 64)
            __builtin_nontemporal_store(((f32x4*)sb)[j], &dnc[j]);
    } else {
        float* dfr = out + wbase * 3;
        for (int j = lane; j < nval * 3; j += 64)
            __builtin_nontemporal_store(sc[j], &dfr[j]);
        float* dnf = out + OFF2 + wbase * 13;
        for (int j = lane; j < nval * 13; j += 64)
            __builtin_nontemporal_store(sb[j], &dnf[j]);
        float* dnc = out + OFF3 + wbase * 13;
        if (lane < nval)
            for (int k = 0; k < 13; ++k) sb[13 * lane + k] = ncv[k];
        for (int j = lane; j < nval * 13; j += 64)
            __builtin_nontemporal_store(sb[j], &dnc[j]);
    }
}

// Hist: quarter histograms, 256 blocks (64 slices x 4 quarters) x 512 threads.
__global__ __launch_bounds__(512) void hist_kernel(
    const float* __restrict__ flatf, unsigned int* __restrict__ parts, int N)
{
    __shared__ unsigned int h[QWORDS];      // 27.4 KB
    const int t = threadIdx.x;
    const int q = blockIdx.x & 3;           // bucket quarter
    const int slice = blockIdx.x >> 2;      // atom slice (64)
    const int lo = q * QTR;

    for (int j = t; j < QWORDS; j += 512) h[j] = 0u;
    __syncthreads();

    for (long long i = (long long)slice * 512 + t; i < N;
         i += (long long)NSLICE * 512) {
        int f = (int)flatf[i] - lo;
        if ((unsigned)f < (unsigned)QTR)
            atomicAdd(&h[f >> 1], 1u << ((f & 1) * 16));
    }
    __syncthreads();

    unsigned int* dst = parts + (long long)blockIdx.x * QWORDS;
    for (int j = t; j < QWORDS; j += 512) dst[j] = h[j];   // PLAIN: re-read next
}

// Reduce: word w -> buckets (2w, 2w+1); block covers exactly 2 scan-chunks,
// emits cnt + countf + chunksum.
__global__ __launch_bounds__(256) void reduce_kernel(
    const unsigned int* __restrict__ parts, int* __restrict__ cnt,
    float* __restrict__ out_count, int* __restrict__ chunksum)
{
    __shared__ int lds[256];
    const int t = threadIdx.x;
    const int wrd = blockIdx.x * 256 + t;   // [0, TOTAL/2)
    int pair = 0;
    if (wrd < TOTAL / 2) {
        const int q = wrd / QWORDS, j = wrd - q * QWORDS;
        unsigned int sum = 0;
#pragma unroll 8
        for (int s = 0; s < NSLICE; ++s)
            sum += parts[(long long)(4 * s + q) * QWORDS + j];
        const int b = q * QTR + 2 * j;
        const int c0 = (int)(sum & 0xFFFFu), c1 = (int)(sum >> 16);
        cnt[b] = c0;  cnt[b + 1] = c1;
        __builtin_nontemporal_store((float)c0, &out_count[b]);
        __builtin_nontemporal_store((float)c1, &out_count[b + 1]);
        pair = c0 + c1;
    }
    lds[t] = pair;
    __syncthreads();
    // two independent 128-thread tree reductions (chunk A = t<128, B = t>=128)
    for (int off = 64; off > 0; off >>= 1) {
        if ((t & 127) < off) lds[t] += lds[t + off];
        __syncthreads();
    }
    if (t == 0)   chunksum[2 * blockIdx.x]     = lds[0];
    if (t == 128) chunksum[2 * blockIdx.x + 1] = lds[128];
}

// Scan: 215 blocks; LDS-scan the 215 chunksums, then intra-chunk scan.
__global__ __launch_bounds__(256) void scan_kernel(
    const int* __restrict__ cnt, const int* __restrict__ chunksum,
    float* __restrict__ out_cum)
{
    __shared__ int lds[256];
    const int t = threadIdx.x;
    const int ch = blockIdx.x;

    lds[t] = (t < ch && t < NCHUNK) ? chunksum[t] : 0;
    __syncthreads();
    for (int off = 128; off > 0; off >>= 1) {
        if (t < off) lds[t] += lds[t + off];
        __syncthreads();
    }
    const int blockpre = lds[0];
    __syncthreads();

    const int idx = ch * 256 + t;
    const int c = (idx < TOTAL) ? cnt[idx] : 0;
    lds[t] = c;
    __syncthreads();
    for (int off = 1; off < 256; off <<= 1) {
        int vp = (t >= off) ? lds[t - off] : 0;
        __syncthreads();
        lds[t] += vp;
        __syncthreads();
    }
    if (idx < TOTAL)
        __builtin_nontemporal_store((float)(blockpre + lds[t] - c), &out_cum[idx]);
}

extern "C" void kernel_launch(void* const* d_in, const int* in_sizes, int n_in,
                              void* d_out, int out_size, void* d_ws, size_t ws_size,
                              hipStream_t stream)
{
    const float* coords = (const float*)d_in[0];
    const float* cell   = (const float*)d_in[1];
    float* out = (float*)d_out;
    unsigned int* parts = (unsigned int*)d_ws;          // 256*QWORDS u32 = 7 MB
    int* cnt = (int*)(parts + 4LL * NSLICE * QWORDS);
    int* chunksum = cnt + TOTAL;

    int N = (int)((out_size - 2 * TOTAL) / 30);         // out_size = 30N + 2*TOTAL

    cell_atoms_kernel<<<(N + BS - 1) / BS, BS, 0, stream>>>(coords, cell, out, N);

    long long off4 = 30LL * N;  // count then cumcount at the tail
    hist_kernel<<<4 * NSLICE, 512, 0, stream>>>(out + 3LL * N, parts, N);
    reduce_kernel<<<(TOTAL / 2 + 255) / 256, 256, 0, stream>>>(
        parts, cnt, out + off4, chunksum);
    scan_kernel<<<NCHUNK, 256, 0, stream>>>(cnt, chunksum, out + off4 + TOTAL);
}

// Round 19
// 46.384 us; speedup vs baseline: 1.0812x; 1.0812x over previous
//
#include <hip/hip_runtime.h>

#define GDIM 38
#define GG   (GDIM * GDIM)          // 1444
#define TOTAL (GDIM * GDIM * GDIM)  // 54872
#define QTR   (TOTAL / 4)           // 13718 buckets per quarter
#define QWORDS (QTR / 2)            // 6859 packed u32 words per quarter
#define NSLICE 128                  // atom slices for histogram (R17-proven)
#define BS 256
#define NCHUNK ((TOTAL + 255) / 256)   // 215

typedef float f32x4 __attribute__((ext_vector_type(4)));

// packed (disp+1) per k: dx | dy<<8 | dz<<16
__device__ __constant__ unsigned int c_dp[13] = {
    0x010100u, 0x010000u, 0x010001u, 0x010002u,
    0x000200u, 0x000201u, 0x000202u,
    0x000100u, 0x000101u, 0x000102u,
    0x000000u, 0x000001u, 0x000002u};

// translation-case table bit-packed: 5 bits/entry (verified R13/R15/R16/R17)
__device__ __forceinline__ int case_of(int cidx) {
    constexpr unsigned long long W0 = 11ULL | (2ULL << 5) | (8ULL << 15) | (1ULL << 20)
        | (5ULL << 30) | (14ULL << 35) | (12ULL << 45) | (3ULL << 50);
    constexpr unsigned long long W1 = 9ULL | (6ULL << 15) | (15ULL << 20)
        | (13ULL << 30) | (4ULL << 35) | (10ULL << 45) | (17ULL << 50);
    constexpr unsigned long long W2 = 7ULL | (16ULL << 5);
    unsigned long long wv = cidx < 12 ? W0 : (cidx < 24 ? W1 : W2);
    int base = cidx < 12 ? 0 : (cidx < 24 ? 12 : 24);
    return (int)((wv >> (5 * (cidx - base))) & 31ULL);
}

// Atoms: wave-private LDS staging, 16 KB/block -> 8 blocks/CU (32 waves/CU).
// nf/nc share one 832-float buffer (two-pass drain, nc parked in 13 VGPRs).
__global__ __launch_bounds__(BS, 8) void cell_atoms_kernel(
    const float* __restrict__ coords, const float* __restrict__ cell,
    float* __restrict__ out, int N)
{
    __shared__ float s[4096];               // 16 KB: 4 waves x (192 + 832)
    const int tid = threadIdx.x;
    const int w = tid >> 6, lane = tid & 63;
    const long long wbase = (long long)blockIdx.x * BS + 64 * w;
    if (wbase >= N) return;

    float* sc = s + 1024 * w;               // 192 floats: coords -> frac in place
    float* sb = sc + 192;                   // 832 floats: nf then nc

    const long long OFF1 = 3LL * N, OFF2 = 4LL * N, OFF3 = 17LL * N;
    const bool fullwave = (wbase + 64 <= N);
    const int nval = fullwave ? 64 : (int)(N - wbase);

    if (fullwave) {
        const f32x4* src = (const f32x4*)(coords + wbase * 3);
        if (lane < 48) ((f32x4*)sc)[lane] = src[lane];
    } else {
        const float* src = coords + wbase * 3;
        for (int j = lane; j < nval * 3; j += 64) sc[j] = src[j];
    }

    float ncv[13];
    if (lane < nval) {
        const float d0 = cell[0], d4 = cell[4], d8 = cell[8];
        int v[3];
#pragma unroll
        for (int a = 0; a < 3; ++a) {
            float d = (a == 0) ? d0 : (a == 1 ? d4 : d8);
            float f = sc[3 * lane + a] / d;   // IEEE divide, matches jnp
            f = f - floorf(f);
            if (f >= 1.0f) f -= 1.0f;
            if (f < 0.0f)  f += 1.0f;
            sc[3 * lane + a] = f;             // frac in place
            v[a] = (int)floorf(f * (float)GDIM);
        }
        int flat = v[0] * GG + v[1] * GDIM + v[2];
        out[OFF1 + wbase + lane] = (float)flat;   // PLAIN: re-read by hist (L2)

#pragma unroll
        for (int k = 0; k < 13; ++k) {
            const unsigned int dp = c_dp[k];
            const int n0 = v[0] + (int)(dp & 0xFFu);
            const int n1 = v[1] + (int)((dp >> 8) & 0xFFu);
            const int n2 = v[2] + (int)((dp >> 16) & 0xFFu);
            const int m0 = (n0 == 0) ? (GDIM - 1) : ((n0 == GDIM + 1) ? 0 : n0 - 1);
            const int m1 = (n1 == 0) ? (GDIM - 1) : ((n1 == GDIM + 1) ? 0 : n1 - 1);
            const int m2 = (n2 == 0) ? (GDIM - 1) : ((n2 == GDIM + 1) ? 0 : n2 - 1);
            const int c0 = (n0 == 0) ? 0 : ((n0 == GDIM + 1) ? 2 : 1);
            const int c1 = (n1 == 0) ? 0 : ((n1 == GDIM + 1) ? 2 : 1);
            const int c2 = (n2 == 0) ? 0 : ((n2 == GDIM + 1) ? 2 : 1);
            sb[13 * lane + k] = (float)(m0 * GG + m1 * GDIM + m2);
            ncv[k] = (float)case_of(c0 * 9 + c1 * 3 + c2);
        }
    }

    if (fullwave) {
        f32x4* dfr = (f32x4*)(out + wbase * 3);
        if (lane < 48) __builtin_nontemporal_store(((f32x4*)sc)[lane], &dfr[lane]);

        f32x4* dnf = (f32x4*)(out + OFF2 + wbase * 13);
#pragma unroll
        for (int j = lane; j < 208; j += 64)
            __builtin_nontemporal_store(((f32x4*)sb)[j], &dnf[j]);

        // reuse sb for nc (same-wave LDS ordering guarantees nf reads done)
#pragma unroll
        for (int k = 0; k < 13; ++k) sb[13 * lane + k] = ncv[k];

        f32x4* dnc = (f32x4*)(out + OFF3 + wbase * 13);
#pragma unroll
        for (int j = lane; j < 208; j += 64)
            __builtin_nontemporal_store(((f32x4*)sb)[j], &dnc[j]);
    } else {
        float* dfr = out + wbase * 3;
        for (int j = lane; j < nval * 3; j += 64)
            __builtin_nontemporal_store(sc[j], &dfr[j]);
        float* dnf = out + OFF2 + wbase * 13;
        for (int j = lane; j < nval * 13; j += 64)
            __builtin_nontemporal_store(sb[j], &dnf[j]);
        float* dnc = out + OFF3 + wbase * 13;
        if (lane < nval)
            for (int k = 0; k < 13; ++k) sb[13 * lane + k] = ncv[k];
        for (int j = lane; j < nval * 13; j += 64)
            __builtin_nontemporal_store(sb[j], &dnc[j]);
    }
}

// Hist: quarter histograms, 512 blocks (128 slices x 4 quarters) x 1024 thr.
__global__ __launch_bounds__(1024) void hist_kernel(
    const float* __restrict__ flatf, unsigned int* __restrict__ parts, int N)
{
    __shared__ unsigned int h[QWORDS];      // 27.4 KB
    const int t = threadIdx.x;
    const int q = blockIdx.x & 3;           // bucket quarter
    const int slice = blockIdx.x >> 2;      // atom slice (128)
    const int lo = q * QTR;

    for (int j = t; j < QWORDS; j += 1024) h[j] = 0u;
    __syncthreads();

    for (long long i = (long long)slice * 1024 + t; i < N;
         i += (long long)NSLICE * 1024) {
        int f = (int)flatf[i] - lo;
        if ((unsigned)f < (unsigned)QTR)
            atomicAdd(&h[f >> 1], 1u << ((f & 1) * 16));
    }
    __syncthreads();

    unsigned int* dst = parts + (long long)blockIdx.x * QWORDS;
    for (int j = t; j < QWORDS; j += 1024) dst[j] = h[j];  // PLAIN: re-read next
}

// Reduce: word w -> buckets (2w, 2w+1); block covers exactly 2 scan-chunks,
// emits cnt + countf + chunksum.
__global__ __launch_bounds__(256) void reduce_kernel(
    const unsigned int* __restrict__ parts, int* __restrict__ cnt,
    float* __restrict__ out_count, int* __restrict__ chunksum)
{
    __shared__ int lds[256];
    const int t = threadIdx.x;
    const int wrd = blockIdx.x * 256 + t;   // [0, TOTAL/2)
    int pair = 0;
    if (wrd < TOTAL / 2) {
        const int q = wrd / QWORDS, j = wrd - q * QWORDS;
        unsigned int sum = 0;
#pragma unroll 8
        for (int s = 0; s < NSLICE; ++s)
            sum += parts[(long long)(4 * s + q) * QWORDS + j];
        const int b = q * QTR + 2 * j;
        const int c0 = (int)(sum & 0xFFFFu), c1 = (int)(sum >> 16);
        cnt[b] = c0;  cnt[b + 1] = c1;
        __builtin_nontemporal_store((float)c0, &out_count[b]);
        __builtin_nontemporal_store((float)c1, &out_count[b + 1]);
        pair = c0 + c1;
    }
    lds[t] = pair;
    __syncthreads();
    // two independent 128-thread tree reductions (chunk A = t<128, B = t>=128)
    for (int off = 64; off > 0; off >>= 1) {
        if ((t & 127) < off) lds[t] += lds[t + off];
        __syncthreads();
    }
    if (t == 0)   chunksum[2 * blockIdx.x]     = lds[0];
    if (t == 128) chunksum[2 * blockIdx.x + 1] = lds[128];
}

// Scan: 215 blocks; LDS-scan the 215 chunksums, then intra-chunk scan.
__global__ __launch_bounds__(256) void scan_kernel(
    const int* __restrict__ cnt, const int* __restrict__ chunksum,
    float* __restrict__ out_cum)
{
    __shared__ int lds[256];
    const int t = threadIdx.x;
    const int ch = blockIdx.x;

    lds[t] = (t < ch && t < NCHUNK) ? chunksum[t] : 0;
    __syncthreads();
    for (int off = 128; off > 0; off >>= 1) {
        if (t < off) lds[t] += lds[t + off];
        __syncthreads();
    }
    const int blockpre = lds[0];
    __syncthreads();

    const int idx = ch * 256 + t;
    const int c = (idx < TOTAL) ? cnt[idx] : 0;
    lds[t] = c;
    __syncthreads();
    for (int off = 1; off < 256; off <<= 1) {
        int vp = (t >= off) ? lds[t - off] : 0;
        __syncthreads();
        lds[t] += vp;
        __syncthreads();
    }
    if (idx < TOTAL)
        __builtin_nontemporal_store((float)(blockpre + lds[t] - c), &out_cum[idx]);
}

extern "C" void kernel_launch(void* const* d_in, const int* in_sizes, int n_in,
                              void* d_out, int out_size, void* d_ws, size_t ws_size,
                              hipStream_t stream)
{
    const float* coords = (const float*)d_in[0];
    const float* cell   = (const float*)d_in[1];
    float* out = (float*)d_out;
    unsigned int* parts = (unsigned int*)d_ws;          // 512*QWORDS u32 = 14 MB
    int* cnt = (int*)(parts + 4LL * NSLICE * QWORDS);
    int* chunksum = cnt + TOTAL;

    int N = (int)((out_size - 2 * TOTAL) / 30);         // out_size = 30N + 2*TOTAL

    cell_atoms_kernel<<<(N + BS - 1) / BS, BS, 0, stream>>>(coords, cell, out, N);

    long long off4 = 30LL * N;  // count then cumcount at the tail
    hist_kernel<<<4 * NSLICE, 1024, 0, stream>>>(out + 3LL * N, parts, N);
    reduce_kernel<<<(TOTAL / 2 + 255) / 256, 256, 0, stream>>>(
        parts, cnt, out + off4, chunksum);
    scan_kernel<<<NCHUNK, 256, 0, stream>>>(cnt, chunksum, out + off4 + TOTAL);
}